// Round 1
// baseline (439.737 us; speedup 1.0000x reference)
//
#include <hip/hip_runtime.h>

// Sparsemax along last dim of an (ROWS x D) fp32 matrix.
// Michelot's algorithm: tau_0 = (sum - 1)/D; iterate
//   S = {x > tau}, tau = (sum_S - 1)/|S|
// until |S| stops changing. Exact (finite convergence), no sort needed.
//
// One 256-thread block per row; each thread keeps 32 elements in registers
// (8 x float4). Single HBM read pass + single write pass => memory-bound.

#define D 8192
#define BLOCK 256
#define VEC 8  // 8 float4 per thread = 32 elements

__global__ __launch_bounds__(BLOCK) void sparsemax_kernel(
    const float* __restrict__ x, float* __restrict__ out) {
  const long long row = blockIdx.x;
  const float4* __restrict__ xr = (const float4*)(x + row * (long long)D);
  float4* __restrict__ outr = (float4*)(out + row * (long long)D);
  const int tid = threadIdx.x;
  const int lane = tid & 63;
  const int wave = tid >> 6;

  // Load row into registers, coalesced float4.
  float4 v[VEC];
#pragma unroll
  for (int i = 0; i < VEC; ++i) v[i] = xr[tid + i * BLOCK];

  __shared__ float red_s[4];
  __shared__ float red_c[4];
  __shared__ float sh_tau;
  __shared__ float sh_cnt;

  // ---- initial tau = (sum(x) - 1) / D ----
  float ps = 0.f;
#pragma unroll
  for (int i = 0; i < VEC; ++i) ps += (v[i].x + v[i].y) + (v[i].z + v[i].w);
#pragma unroll
  for (int o = 32; o > 0; o >>= 1) ps += __shfl_down(ps, o, 64);
  if (lane == 0) red_s[wave] = ps;
  __syncthreads();
  if (tid == 0) {
    float tot = (red_s[0] + red_s[1]) + (red_s[2] + red_s[3]);
    sh_tau = (tot - 1.0f) * (1.0f / (float)D);
  }
  __syncthreads();
  float tau = sh_tau;
  float prev_c = (float)D;

  // ---- Michelot iterations ----
  for (int iter = 0; iter < 48; ++iter) {
    float s = 0.f, c = 0.f;
#pragma unroll
    for (int i = 0; i < VEC; ++i) {
      if (v[i].x > tau) { s += v[i].x; c += 1.f; }
      if (v[i].y > tau) { s += v[i].y; c += 1.f; }
      if (v[i].z > tau) { s += v[i].z; c += 1.f; }
      if (v[i].w > tau) { s += v[i].w; c += 1.f; }
    }
#pragma unroll
    for (int o = 32; o > 0; o >>= 1) {
      s += __shfl_down(s, o, 64);
      c += __shfl_down(c, o, 64);
    }
    if (lane == 0) { red_s[wave] = s; red_c[wave] = c; }
    __syncthreads();
    if (tid == 0) {
      float ts = (red_s[0] + red_s[1]) + (red_s[2] + red_s[3]);
      float tc = (red_c[0] + red_c[1]) + (red_c[2] + red_c[3]);
      sh_tau = (ts - 1.0f) / tc;  // tc >= 1 always (max stays in support)
      sh_cnt = tc;
    }
    __syncthreads();
    tau = sh_tau;
    float cnt = sh_cnt;
    if (cnt == prev_c) break;  // support stable => tau exact; uniform branch
    prev_c = cnt;
  }

  // ---- epilogue: out = max(x - tau, 0) ----
#pragma unroll
  for (int i = 0; i < VEC; ++i) {
    float4 o;
    o.x = fmaxf(v[i].x - tau, 0.f);
    o.y = fmaxf(v[i].y - tau, 0.f);
    o.z = fmaxf(v[i].z - tau, 0.f);
    o.w = fmaxf(v[i].w - tau, 0.f);
    outr[tid + i * BLOCK] = o;
  }
}

extern "C" void kernel_launch(void* const* d_in, const int* in_sizes, int n_in,
                              void* d_out, int out_size, void* d_ws, size_t ws_size,
                              hipStream_t stream) {
  const float* x = (const float*)d_in[0];
  float* out = (float*)d_out;
  const int rows = in_sizes[0] / D;  // 8192
  sparsemax_kernel<<<rows, BLOCK, 0, stream>>>(x, out);
}